// Round 8
// baseline (222.860 us; speedup 1.0000x reference)
//
#include <hip/hip_runtime.h>

// GraphEmbedder: B=8, C=64, G=65536, 4 layers of y=lrelu(W@[x; x-x0]), then max over G.
// Identity: W@[x; x-x0] = Wa@x - Wb@x0, Wa = W[:,:64]+W[:,64:], Wb = W[:,64:].
// R15 = R14 (T3/T4 counted-vmcnt pipeline) with the macro paren bug fixed:
//  - 3 staging buffers (17 KB each), depth-2 prefetch: stage pass p+2 right after the
//    pass-p barrier; s_waitcnt vmcnt(4) (NEVER 0 in steady state) + raw s_barrier.
//    R13 drained vmcnt(0) at every pass (16x) -- the m233-measured 2-phase stall.
//  - race-free by construction: stage at p targets the buffer last read at p-1; all
//    waves are past that read at p's barrier; per-wave vmcnt(4)-before-barrier ensures
//    everyone's pass-p loads landed before anyone computes.
//  - LDS budget for 2 blocks/CU: layer-0 weights in VGPRs (32 regs, total ~100 << 128
//    spill cliff of R9/R11/R12), layers 1-3 in 24 KB LDS image.
//    stg 52224 + lwf 24576 + lbias 1024 + blockmax 1024 = 78848 B <= 80 KB.
//  - T5 setprio(1) around the MFMA chain (phase-split structure exists now).
//  - XCD-bijective swizzle kept (FETCH 141->94 MB in R12).

#define G_TOT 65536

typedef _Float16 hf2 __attribute__((ext_vector_type(2)));
typedef _Float16 hf4 __attribute__((ext_vector_type(4)));
typedef _Float16 hf8 __attribute__((ext_vector_type(8)));
typedef float float4_ __attribute__((ext_vector_type(4)));

static __device__ __forceinline__ hf2 pkh(float x, float y) {
    return __builtin_bit_cast(hf2, __builtin_amdgcn_cvt_pkrtz(x, y));
}

// ws layout (floats):
//   [0, 8192)       wf16: 16384 f16 weight fragments, frag-major
//                   elem (f*512 + lane*8 + e) = f16(Wa[l][16*mt+(lane&15)][32*pr+16*(e>>2)+4*(lane>>4)+(e&3)])
//                   with f = ((l*4+mt)*2+pr)
//   [16384, 18432)  nbias[b][l][o] fp32 (NEGATED bias)
//   [18432, 18944)  maxenc (uint32 ordered-float), zeroed by prep

__global__ __launch_bounds__(256) void ge_prep(
    const float* __restrict__ feat,
    const float* __restrict__ W0, const float* __restrict__ W1,
    const float* __restrict__ W2, const float* __restrict__ W3,
    float* __restrict__ ws)
{
    const int tid = threadIdx.x;
    const int blk = blockIdx.x;
    __shared__ float lw[64][129];
    __shared__ float x0[2][64];

    if (blk == 8) {
        // maxenc init + f16 fragment image of Wa = W[:,:64] + W[:,64:]
        unsigned* maxenc = (unsigned*)(ws + 18432);
        maxenc[tid] = 0u; maxenc[tid + 256] = 0u;
        _Float16* wf = (_Float16*)ws;
        for (int ci = tid; ci < 8192; ci += 256) {       // ci indexes hf2 chunks
            int f = ci >> 8, ln = (ci >> 2) & 63, h2 = ci & 3;
            int l = f >> 3, mt = (f >> 1) & 3, pr = f & 1;
            int o = (mt << 4) + (ln & 15);
            int c = (pr << 5) + ((h2 >> 1) << 4) + ((ln >> 4) << 2) + ((h2 & 1) << 1);
            const float* Wl = (l == 0) ? W0 : (l == 1) ? W1 : (l == 2) ? W2 : W3;
            float a0 = Wl[o * 128 + c]     + Wl[o * 128 + 64 + c];
            float a1 = Wl[o * 128 + c + 1] + Wl[o * 128 + 64 + c + 1];
            *(hf2*)&wf[ci << 1] = pkh(a0, a1);
        }
        return;
    }

    // blocks 0..7: exact fp32 bias chain for batch b = blk
    const int b = blk;
    if (tid < 64) x0[0][tid] = feat[(size_t)(b * 64 + tid) * G_TOT];
    float* nbias = ws + 16384;
    for (int l = 0; l < 4; ++l) {
        const float* Wl = (l == 0) ? W0 : (l == 1) ? W1 : (l == 2) ? W2 : W3;
        for (int i = tid; i < 64 * 128; i += 256) lw[i >> 7][i & 127] = Wl[i];
        __syncthreads();
        if (tid < 64) {
            const int o = tid;
            const float* src = x0[l & 1];
            float s1 = 0.f, s2 = 0.f;
            for (int c = 0; c < 64; ++c) {
                float xv = src[c];
                s1 += lw[o][c] * xv;
                s2 += lw[o][64 + c] * xv;
            }
            nbias[b * 256 + l * 64 + o] = -s2;          // negated, [b][l][o]
            x0[(l & 1) ^ 1][o] = fmaxf(s1, 0.1f * s1);
        }
        __syncthreads();
    }
}

// 4-layer MFMA chain on fragment array BF (hf4[4]); layer-0 weights from VGPR wfr0,
// layers 1-3 from LDS image lwf. Raw layer-3 max into rmax. All indices static.
#define COMPUTE_TILE(BF)                                                              \
    _Pragma("unroll")                                                                 \
    for (int l = 0; l < 4; ++l) {                                                     \
        float4_ acc[4];                                                               \
        _Pragma("unroll")                                                             \
        for (int mt = 0; mt < 4; ++mt) {                                              \
            if (l < 3) acc[mt] = *(const float4_*)&lbias[(l << 6) + (mt << 4) + (q << 2)]; \
            else       acc[mt] = float4_{0.f, 0.f, 0.f, 0.f};                         \
        }                                                                             \
        _Pragma("unroll")                                                             \
        for (int mt = 0; mt < 4; ++mt) {                                              \
            _Pragma("unroll")                                                         \
            for (int pr = 0; pr < 2; ++pr) {                                          \
                union { hf8 h8; hf4 h4[2]; } ua;                                      \
                if (l == 0) ua.h8 = wfr0[mt][pr];                                     \
                else ua.h8 = *(const hf8*)&lwf[(((((((l - 1) << 2) + mt) << 1) + pr) << 6) + lane) * 8]; \
                acc[mt] = __builtin_amdgcn_mfma_f32_16x16x16f16(ua.h4[0], BF[(pr << 1) + 0], acc[mt], 0, 0, 0); \
                acc[mt] = __builtin_amdgcn_mfma_f32_16x16x16f16(ua.h4[1], BF[(pr << 1) + 1], acc[mt], 0, 0, 0); \
            }                                                                         \
        }                                                                             \
        if (l < 3) {                                                                  \
            _Pragma("unroll")                                                         \
            for (int mt = 0; mt < 4; ++mt) {                                          \
                union { hf2 h2[2]; hf4 h4; } u;                                       \
                u.h2[0] = pkh(acc[mt][0], acc[mt][1]);                                \
                u.h2[1] = pkh(acc[mt][2], acc[mt][3]);                                \
                hf4 h = u.h4;                                                         \
                h = __builtin_elementwise_max(h, h * k01);                            \
                BF[mt] = h;                                                           \
            }                                                                         \
        } else {                                                                      \
            _Pragma("unroll")                                                         \
            for (int mt = 0; mt < 4; ++mt)                                            \
                _Pragma("unroll")                                                     \
                for (int j = 0; j < 4; ++j)                                           \
                    rmax[mt][j] = fmaxf(rmax[mt][j], acc[mt][j]);                     \
        }                                                                             \
    }

// stage one 64-col pass into LDS buffer at float-offset BUFBASE:
// instr j stages group G=(w<<2)+j = rows 4G..4G+3 x 64 cols as a linear 1KB block
// (HW: dst_base + lane*16; lane's 16B = row 4G+(lane>>4), cols 4*(lane&15)..+3).
// Global src per-lane: dense 256B run per row. PCOL = pass column offset (floats).
#define STAGE(PCOL, BUFBASE)                                                          \
    _Pragma("unroll")                                                                 \
    for (int j = 0; j < 4; ++j) {                                                     \
        const int G_ = (w << 2) + j;                                                  \
        const float* src_ = Fbase + (size_t)((G_ << 2) + (lane >> 4)) * G_TOT         \
                          + (PCOL) + ((lane & 15) << 2);                              \
        __builtin_amdgcn_global_load_lds(                                             \
            (const __attribute__((address_space(1))) unsigned*)src_,                  \
            (__attribute__((address_space(3))) unsigned*)&stg[(BUFBASE) + G_ * 272],  \
            16, 0, 0);                                                                \
    }

__global__ __launch_bounds__(256, 2) void ge_main(
    const float* __restrict__ feat,
    const float* __restrict__ ws_wf,
    const float* __restrict__ nbias,
    unsigned* __restrict__ maxenc)
{
    // 3 buffers x 16 groups x (4 rows x 64 cols + 16 floats pad) = 52224 B
    __shared__ __align__(16) float stg[3 * 16 * 272];
    __shared__ __align__(16) _Float16 lwf[12288];       // layers 1-3 fragment image, 24 KB
    __shared__ float lbias[256];
    __shared__ float blockmax[4][64];
    const int tid = threadIdx.x;

    // XCD-bijective swizzle: each XCD's 64 resident blocks cover exactly one batch
    const int nb = ((blockIdx.x & 7) << 6) | (blockIdx.x >> 3);
    const int b = nb >> 6;
    const int w = tid >> 6, lane = tid & 63, q = lane >> 4, n = lane & 15;

    const float* Fbase = feat + (size_t)b * 64 * G_TOT + (size_t)((nb & 63) << 10);

    // ---- prologue ----
    // L2-resident small loads FIRST (so pass-0/1 stages are the newest vmcnt entries)
    hf8 wfr0[4][2];
    {
        const hf8* wp = (const hf8*)ws_wf;
#pragma unroll
        for (int mt = 0; mt < 4; ++mt)
#pragma unroll
            for (int pr = 0; pr < 2; ++pr)
                wfr0[mt][pr] = wp[(((mt << 1) + pr) << 6) + lane];
    }
    {   // layers 1-3 fragment image -> LDS (floats [2048, 8192) of ws_wf)
        const float4_* wp4 = (const float4_*)ws_wf;
#pragma unroll
        for (int k = 0; k < 6; ++k) {
            int i = tid + (k << 8);
            *(float4_*)&lwf[i << 3] = wp4[512 + i];
        }
    }
    lbias[tid] = nbias[(b << 8) + tid];

    // depth-2 prefetch: passes 0 and 1 in flight
    STAGE(0, 0)
    STAGE(64, 4352)

    float rmax[4][4];
#pragma unroll
    for (int mt = 0; mt < 4; ++mt)
#pragma unroll
        for (int j = 0; j < 4; ++j) rmax[mt][j] = -__builtin_inff();

    const hf4 k01 = { (_Float16)0.1f, (_Float16)0.1f, (_Float16)0.1f, (_Float16)0.1f };

    // ---- main loop: 16 passes of 64 cols; counted vmcnt, raw barrier, 3-buffer ring ----
    int rb = 0, sb = 8704;          // read base (pass p), stage base (pass p+2)
#pragma unroll 1
    for (int p = 0; p < 16; ++p) {
        // wait for THIS wave's pass-p loads (4 newest stay in flight), then barrier:
        // after it, every wave's pass-p groups are in LDS. lgkmcnt(0) covers prologue
        // ds_writes at p==0 (harmless later: compute ds_reads must finish anyway).
        if (p < 15) asm volatile("s_waitcnt vmcnt(4) lgkmcnt(0)" ::: "memory");
        else        asm volatile("s_waitcnt vmcnt(0) lgkmcnt(0)" ::: "memory");
        __builtin_amdgcn_sched_barrier(0);
        __builtin_amdgcn_s_barrier();
        __builtin_amdgcn_sched_barrier(0);
        // stage pass p+2 into the buffer last read at p-1 (all waves past it)
        if (p < 14) { STAGE((p + 2) << 6, sb) }
        // feature fragments: rows 16kf+4q+r (group 4kf+q, row r), col 16w+n
        hf4 bf[4];
#pragma unroll
        for (int kf = 0; kf < 4; ++kf) {
            const int gb = rb + ((kf << 2) + q) * 272 + (w << 4) + n;
            float f0 = stg[gb];
            float f1 = stg[gb + 64];
            float f2 = stg[gb + 128];
            float f3 = stg[gb + 192];
            union { hf2 h2[2]; hf4 h4; } u;
            u.h2[0] = pkh(f0, f1); u.h2[1] = pkh(f2, f3);
            bf[kf] = u.h4;
        }
        __builtin_amdgcn_s_setprio(1);
        COMPUTE_TILE(bf)
        __builtin_amdgcn_s_setprio(0);
        rb = (rb == 8704) ? 0 : rb + 4352;
        sb = (sb == 8704) ? 0 : sb + 4352;
    }

    // ---- reduce raw max over 16 column-lanes ----
#pragma unroll
    for (int mt = 0; mt < 4; ++mt)
#pragma unroll
        for (int j = 0; j < 4; ++j) {
            float v = rmax[mt][j];
            v = fmaxf(v, __shfl_xor(v, 1, 64));
            v = fmaxf(v, __shfl_xor(v, 2, 64));
            v = fmaxf(v, __shfl_xor(v, 4, 64));
            v = fmaxf(v, __shfl_xor(v, 8, 64));
            rmax[mt][j] = v;
        }
    if (n == 0) {
#pragma unroll
        for (int mt = 0; mt < 4; ++mt)
#pragma unroll
            for (int j = 0; j < 4; ++j)
                blockmax[w][(mt << 4) + (q << 2) + j] = rmax[mt][j];
    }
    __syncthreads();
    if (tid < 64) {
        float v = fmaxf(fmaxf(blockmax[0][tid], blockmax[1][tid]),
                        fmaxf(blockmax[2][tid], blockmax[3][tid]));
        unsigned s = __float_as_uint(v);
        unsigned enc = (s & 0x80000000u) ? ~s : (s | 0x80000000u);
        atomicMax(&maxenc[b * 64 + tid], enc);
    }
}

__global__ void ge_final(const unsigned* __restrict__ maxenc,
                         const float* __restrict__ nbias,
                         float* __restrict__ out)
{
    int i = threadIdx.x;
    if (i < 512) {
        unsigned u = maxenc[i];
        unsigned s = (u & 0x80000000u) ? (u ^ 0x80000000u) : ~u;
        // deferred layer-3 bias + leaky-relu (both commute with max over G)
        float v = __uint_as_float(s) + nbias[((i >> 6) << 8) + 192 + (i & 63)];
        out[i] = fmaxf(v, 0.1f * v);
    }
}

extern "C" void kernel_launch(void* const* d_in, const int* in_sizes, int n_in,
                              void* d_out, int out_size, void* d_ws, size_t ws_size,
                              hipStream_t stream) {
    const float* feat = (const float*)d_in[0];
    const float* W0 = (const float*)d_in[1];
    const float* W1 = (const float*)d_in[2];
    const float* W2 = (const float*)d_in[3];
    const float* W3 = (const float*)d_in[4];
    float* ws = (float*)d_ws;
    unsigned* maxenc = (unsigned*)(ws + 18432);

    ge_prep<<<9, 256, 0, stream>>>(feat, W0, W1, W2, W3, ws);
    ge_main<<<512, 256, 0, stream>>>(feat, ws, ws + 16384, maxenc);
    ge_final<<<1, 512, 0, stream>>>(maxenc, ws + 16384, (float*)d_out);
}